// Round 3
// baseline (1292.237 us; speedup 1.0000x reference)
//
#include <hip/hip_runtime.h>
#include <math.h>

typedef __bf16 bf16;
typedef __bf16 bf16x8 __attribute__((ext_vector_type(8)));
typedef __bf16 bf16x4 __attribute__((ext_vector_type(4)));
typedef float f32x4 __attribute__((ext_vector_type(4)));

#define NROW 8192
#define BHALF 4096
#define DFE 2048
#define DP 256
#define NCLS 1000

#define LOGITS_N 8191
#define OUT_LOGITS 2
#define OUT_LABELS (2 + 8192 * 8191)
#define OUT_LIDS32 (OUT_LABELS + 8192)
#define OUT_LIDS512 (OUT_LIDS32 + 8192)

#define G0TILES 528   // mode-0: 256x256 tiles, upper triangle (tm <= tn), 32x32 tile grid
#define G1TILES 1024  // mode-1: 32 x 32 full grid (logits), 256x256 tiles

// async 16B global->LDS (dest = wave-uniform base + lane*16)
__device__ inline void gload16(const bf16* g, bf16* l) {
    __builtin_amdgcn_global_load_lds((const __attribute__((address_space(1))) void*)g,
                                     (__attribute__((address_space(3))) void*)l, 16, 0, 0);
}

// ---------------- init: zero scalar accumulators + write labels ----------------
__global__ __launch_bounds__(256) void init_kernel(float* out) {
    int i = blockIdx.x * 256 + threadIdx.x;
    if (i < 2) out[i] = 0.f;
    if (i < NROW) out[(size_t)OUT_LABELS + i] = (float)(i & (BHALF - 1));
}

// ---------------- split fe into bf16 hi/lo + row norms ----------------
__global__ __launch_bounds__(256) void split_fe_kernel(const float* __restrict__ fe0,
                                                       const float* __restrict__ fe1,
                                                       bf16* __restrict__ feh,
                                                       bf16* __restrict__ fel,
                                                       float* __restrict__ norms) {
    int row = blockIdx.x, tid = threadIdx.x;
    const float* src = (row < BHALF) ? fe0 + (size_t)row * DFE
                                     : fe1 + (size_t)(row - BHALF) * DFE;
    float ss = 0.f;
#pragma unroll
    for (int pass = 0; pass < 2; ++pass) {
        int c = (pass * 256 + tid) * 4;
        float4 v = *(const float4*)(src + c);
        ss += v.x * v.x + v.y * v.y + v.z * v.z + v.w * v.w;
        bf16 h0 = (bf16)v.x, h1 = (bf16)v.y, h2 = (bf16)v.z, h3 = (bf16)v.w;
        bf16 l0 = (bf16)(v.x - (float)h0), l1 = (bf16)(v.y - (float)h1);
        bf16 l2 = (bf16)(v.z - (float)h2), l3 = (bf16)(v.w - (float)h3);
        bf16x4 hv = {h0, h1, h2, h3};
        bf16x4 lv = {l0, l1, l2, l3};
        *(bf16x4*)(feh + (size_t)row * DFE + c) = hv;
        *(bf16x4*)(fel + (size_t)row * DFE + c) = lv;
    }
#pragma unroll
    for (int off = 32; off; off >>= 1) ss += __shfl_down(ss, off);
    __shared__ float red[4];
    if ((tid & 63) == 0) red[tid >> 6] = ss;
    __syncthreads();
    if (tid == 0) norms[row] = red[0] + red[1] + red[2] + red[3];
}

// ---------------- l2-normalize p -> bf16 (HH-only logits path) ----------------
__global__ __launch_bounds__(256) void norm_split_p_kernel(const float* __restrict__ p0,
                                                           const float* __restrict__ p1,
                                                           bf16* __restrict__ oh) {
    int row = blockIdx.x, tid = threadIdx.x;
    const float* src = (row < BHALF) ? p0 + (size_t)row * DP
                                     : p1 + (size_t)(row - BHALF) * DP;
    float x = src[tid];
    float ss = x * x;
#pragma unroll
    for (int off = 32; off; off >>= 1) ss += __shfl_down(ss, off);
    __shared__ float red[4];
    if ((tid & 63) == 0) red[tid >> 6] = ss;
    __syncthreads();
    float tot = red[0] + red[1] + red[2] + red[3];
    float rn = 1.f / fmaxf(sqrtf(tot), 1e-12f);
    oh[(size_t)row * DP + tid] = (bf16)(x * rn);
}

// ---------------- BYOL main loss ----------------
__device__ inline float dot4(float4 a, float4 b) {
    return a.x * b.x + a.y * b.y + a.z * b.z + a.w * b.w;
}

__global__ __launch_bounds__(256) void byol_kernel(const float* __restrict__ p0,
                                                   const float* __restrict__ p1,
                                                   const float* __restrict__ z0,
                                                   const float* __restrict__ z1,
                                                   float* out) {
    int tid = threadIdx.x, wave = tid >> 6, lane = tid & 63;
    int row = blockIdx.x * 4 + wave;
    size_t base = (size_t)row * DP + lane * 4;
    float4 a0 = *(const float4*)(p0 + base);
    float4 b0 = *(const float4*)(z1 + base);
    float4 a1 = *(const float4*)(p1 + base);
    float4 b1 = *(const float4*)(z0 + base);
    float pp0 = dot4(a0, a0), zz0 = dot4(b0, b0), pz0 = dot4(a0, b0);
    float pp1 = dot4(a1, a1), zz1 = dot4(b1, b1), pz1 = dot4(a1, b1);
#pragma unroll
    for (int off = 32; off; off >>= 1) {
        pp0 += __shfl_down(pp0, off); zz0 += __shfl_down(zz0, off); pz0 += __shfl_down(pz0, off);
        pp1 += __shfl_down(pp1, off); zz1 += __shfl_down(zz1, off); pz1 += __shfl_down(pz1, off);
    }
    __shared__ float red[4];
    if (lane == 0) {
        float c0 = pz0 / (fmaxf(sqrtf(pp0), 1e-12f) * fmaxf(sqrtf(zz0), 1e-12f));
        float c1 = pz1 / (fmaxf(sqrtf(pp1), 1e-12f) * fmaxf(sqrtf(zz1), 1e-12f));
        red[wave] = (2.f - 2.f * c0) + (2.f - 2.f * c1);
    }
    __syncthreads();
    if (tid == 0) atomicAdd(out, (red[0] + red[1] + red[2] + red[3]) * (1.f / 4096.f));
}

// ---------------- online linear-probe CE loss ----------------
__global__ __launch_bounds__(256) void online_kernel(const float* __restrict__ cls0,
                                                     const float* __restrict__ cls1,
                                                     const int* __restrict__ labels,
                                                     float* out) {
    int tid = threadIdx.x, wave = tid >> 6, lane = tid & 63;
    int row = blockIdx.x * 4 + wave;
    const float* src = (row < BHALF) ? cls0 + (size_t)row * NCLS
                                     : cls1 + (size_t)(row - BHALF) * NCLS;
    int lbl = labels[row & (BHALF - 1)];
    float xs[16];
    float mx = -INFINITY;
#pragma unroll
    for (int j = 0; j < 16; ++j) {
        int c = lane + j * 64;
        xs[j] = (c < NCLS) ? src[c] : -INFINITY;
        mx = fmaxf(mx, xs[j]);
    }
#pragma unroll
    for (int off = 32; off; off >>= 1) mx = fmaxf(mx, __shfl_xor(mx, off));
    float se = 0.f;
#pragma unroll
    for (int j = 0; j < 16; ++j) se += expf(xs[j] - mx);
#pragma unroll
    for (int off = 32; off; off >>= 1) se += __shfl_xor(se, off);
    __shared__ float red[4];
    if (lane == 0) red[wave] = src[lbl] - mx - logf(se);
    __syncthreads();
    if (tid == 0) atomicAdd(out + 1, -(red[0] + red[1] + red[2] + red[3]) * (1.f / 8192.f));
}

// ---------------- 256x256-tile 8-phase GEMM (m201-style port; mode0: d2, mode1: logits) ----
// 8 waves (2M x 4N), per-wave output 128x64 = acc[8][4] (rows mi*128+wr*64+f*16,
// cols ni*128+wn*32+jj*16). LDS 128KB: 2 buf x (A[256][64] + B[256][64]) bf16.
// 4 sub-phases per K-tile, one per C-quadrant (mi,ni) in order (0,0),(0,1),(1,0),(1,1):
//   {ds_read quadrant frags | issue 1 stage-unit | barrier | lgkmcnt(0) | setprio(1)
//    16 MFMA | setprio(0) | counted vmcnt | barrier}
// LDS reads/phase: 12,4,8,0 (B frags of both halves live across the tile; A reloaded).
// Stage units (128rows x 64cols, 2 gload16/wave): P0->A1(t+1) [other buf],
// P1->A0(t+2), P2->B0(t+2), P3->B1(t+2) [same buf, region's last read is a prior phase].
// Ledger: 5 units (10 loads) in flight; vmcnt(10) at end of P0/P1/P3; drain for t>=NT-3.
// XOR-swizzle (verified): phys grp = logical grp ^ (row&7); staging pre-swizzles source.
__global__ __launch_bounds__(512, 2) void gemm_kernel(const bf16* __restrict__ Hp,
                                                      const bf16* __restrict__ Lp,
                                                      const bf16* __restrict__ OHp,
                                                      const float* __restrict__ norms,
                                                      float* __restrict__ d2,
                                                      float* __restrict__ outlog) {
    __shared__ bf16 sm[2][32768];  // per buf: A[256][64] @0, B[256][64] @16384 elts
    int tid = threadIdx.x, lane = tid & 63, wave = tid >> 6;
    int wr = wave >> 2, wn = wave & 3;
    int lrow = lane & 15, lquad = lane >> 4, r7 = lrow & 7, pg = lquad ^ r7;
    int rsub = lane >> 3, grp = lane & 7, lg = grp ^ rsub;

    int bid = blockIdx.x;
    int mode, tm, tn, ksh;
    const bf16 *Hmat, *Lmat;
    int Kd;
    if (bid < G0TILES) {
        mode = 0;
        int sw = (bid & 7) * (G0TILES / 8) + (bid >> 3);  // XCD-bijective (528 = 8*66)
        int i = 0;
        while ((i + 1) * (64 - i) / 2 <= sw) ++i;  // prefix(m) = m*(65-m)/2
        tm = i;
        tn = tm + (sw - i * (65 - i) / 2);
        Hmat = Hp; Lmat = Lp; Kd = DFE; ksh = 5;
    } else {
        mode = 1;
        int id = bid - G0TILES;
        int sw = (id & 7) * (G1TILES / 8) + (id >> 3);    // 1024 = 8*128
        tm = sw & 31; tn = sw >> 5;
        Hmat = OHp; Lmat = OHp; Kd = DP; ksh = 2;
    }
    int NT = (mode == 0 ? 3 : 1) << ksh;  // 96 or 4
    int kmask = (1 << ksh) - 1;
    int arow0 = tm * 256, brow0 = tn * 256;
    size_t delta = (size_t)(Lmat - Hmat);  // 0 in mode 1

    // per-wave staging base (pre-swizzled source: fetch logical group lg for phys grp)
    const bf16* baseA0 = Hmat + (size_t)(arow0 + wave * 8 + rsub) * Kd + lg * 8;
    const bf16* baseB0 = Hmat + (size_t)(brow0 + wave * 8 + rsub) * Kd + lg * 8;

    // fragment LDS byte offsets (ks=1 half is ^64)
    int aoffbase[2], boffbase[2];
    aoffbase[0] = (wr * 64 + lrow) * 128 + pg * 16;
    aoffbase[1] = aoffbase[0] + 128 * 128;
    boffbase[0] = 32768 + (wn * 32 + lrow) * 128 + pg * 16;
    boffbase[1] = boffbase[0] + 128 * 128;

    f32x4 acc[8][4];
    f32x4 zz = {0.f, 0.f, 0.f, 0.f};
#pragma unroll
    for (int i = 0; i < 8; ++i)
#pragma unroll
        for (int j = 0; j < 4; ++j) acc[i][j] = zz;

// stage one 128-row half-unit of A or B of K-tile tau into dstbuf (2 gload16/wave)
#define STAGE_A(tau, h, dstbuf)                                                   \
    do {                                                                          \
        int tau_ = (tau);                                                         \
        if (tau_ < NT) {                                                          \
            int ch_ = tau_ >> ksh;                                                \
            size_t dd_ = (ch_ == 1) ? delta : 0;                                  \
            int k_ = (tau_ & kmask) << 6;                                         \
            bf16* d_ = (dstbuf) + (h) * 8192 + wave * 512;                        \
            gload16(baseA0 + (size_t)((h) * 128) * Kd + dd_ + k_, d_);            \
            gload16(baseA0 + (size_t)((h) * 128 + 64) * Kd + dd_ + k_, d_ + 4096);\
        }                                                                         \
    } while (0)

#define STAGE_B(tau, h, dstbuf)                                                   \
    do {                                                                          \
        int tau_ = (tau);                                                         \
        if (tau_ < NT) {                                                          \
            int ch_ = tau_ >> ksh;                                                \
            size_t dd_ = (ch_ == 2) ? delta : 0;                                  \
            int k_ = (tau_ & kmask) << 6;                                         \
            bf16* d_ = (dstbuf) + 16384 + (h) * 8192 + wave * 512;                \
            gload16(baseB0 + (size_t)((h) * 128) * Kd + dd_ + k_, d_);            \
            gload16(baseB0 + (size_t)((h) * 128 + 64) * Kd + dd_ + k_, d_ + 4096);\
        }                                                                         \
    } while (0)

#define READ_A(AF, MI)                                                            \
    do {                                                                          \
        _Pragma("unroll") for (int f = 0; f < 4; ++f) {                           \
            int off_ = aoffbase[(MI)] + f * 2048;                                 \
            AF[f][0] = *(const bf16x8*)(Sb + off_);                               \
            AF[f][1] = *(const bf16x8*)(Sb + (off_ ^ 64));                        \
        }                                                                         \
    } while (0)

#define READ_B(BF, NI)                                                            \
    do {                                                                          \
        _Pragma("unroll") for (int jj = 0; jj < 2; ++jj) {                        \
            int off_ = boffbase[(NI)] + jj * 2048;                                \
            BF[jj][0] = *(const bf16x8*)(Sb + off_);                              \
            BF[jj][1] = *(const bf16x8*)(Sb + (off_ ^ 64));                       \
        }                                                                         \
    } while (0)

#define MFMA_PHASE(MI, NI, AF, BF)                                                \
    do {                                                                          \
        __builtin_amdgcn_s_setprio(1);                                            \
        _Pragma("unroll") for (int f = 0; f < 4; ++f)                             \
            _Pragma("unroll") for (int jj = 0; jj < 2; ++jj) {                    \
                acc[(MI)*4 + f][(NI)*2 + jj] = __builtin_amdgcn_mfma_f32_16x16x32_bf16( \
                    AF[f][0], BF[jj][0], acc[(MI)*4 + f][(NI)*2 + jj], 0, 0, 0);  \
                acc[(MI)*4 + f][(NI)*2 + jj] = __builtin_amdgcn_mfma_f32_16x16x32_bf16( \
                    AF[f][1], BF[jj][1], acc[(MI)*4 + f][(NI)*2 + jj], 0, 0, 0);  \
            }                                                                     \
        __builtin_amdgcn_s_setprio(0);                                            \
    } while (0)

#define VM_END(tailflag)                                                          \
    do {                                                                          \
        if (tailflag) asm volatile("s_waitcnt vmcnt(0)" ::: "memory");            \
        else          asm volatile("s_waitcnt vmcnt(10)" ::: "memory");           \
    } while (0)

    bf16x8 af[4][2], b0f[2][2], b1f[2][2];

    // prologue ledger order: A0(0),B0(0),B1(0),A1(0),A0(1),B0(1),B1(1) = 14 loads
    STAGE_A(0, 0, sm[0]); STAGE_B(0, 0, sm[0]); STAGE_B(0, 1, sm[0]); STAGE_A(0, 1, sm[0]);
    STAGE_A(1, 0, sm[1]); STAGE_B(1, 0, sm[1]); STAGE_B(1, 1, sm[1]);
    asm volatile("s_waitcnt vmcnt(10)" ::: "memory");  // A0(0),B0(0) landed
    __builtin_amdgcn_s_barrier();

    for (int t = 0; t < NT; ++t) {
        const char* Sb = (const char*)sm[t & 1];
        bf16* samebuf = sm[t & 1];
        bf16* otherbuf = sm[(t + 1) & 1];
        bool tail = (t >= NT - 3);

        // ---- P0 (mi=0, ni=0): read A0 + B0 frags; stage A1(t+1)
        READ_A(af, 0);
        READ_B(b0f, 0);
        STAGE_A(t + 1, 1, otherbuf);
        __builtin_amdgcn_s_barrier();
        asm volatile("s_waitcnt lgkmcnt(0)" ::: "memory");
        __builtin_amdgcn_sched_barrier(0);
        MFMA_PHASE(0, 0, af, b0f);
        VM_END(tail);
        __builtin_amdgcn_s_barrier();

        // ---- P1 (mi=0, ni=1): read B1 frags; stage A0(t+2)
        READ_B(b1f, 1);
        STAGE_A(t + 2, 0, samebuf);
        __builtin_amdgcn_s_barrier();
        asm volatile("s_waitcnt lgkmcnt(0)" ::: "memory");
        __builtin_amdgcn_sched_barrier(0);
        MFMA_PHASE(0, 1, af, b1f);
        VM_END(tail);
        __builtin_amdgcn_s_barrier();

        // ---- P2 (mi=1, ni=0): read A1 frags; stage B0(t+2)
        READ_A(af, 1);
        STAGE_B(t + 2, 0, samebuf);
        __builtin_amdgcn_s_barrier();
        asm volatile("s_waitcnt lgkmcnt(0)" ::: "memory");
        __builtin_amdgcn_sched_barrier(0);
        MFMA_PHASE(1, 0, af, b0f);
        if (tail) asm volatile("s_waitcnt vmcnt(0)" ::: "memory");
        __builtin_amdgcn_s_barrier();

        // ---- P3 (mi=1, ni=1): no reads; stage B1(t+2)
        STAGE_B(t + 2, 1, samebuf);
        __builtin_amdgcn_s_barrier();
        __builtin_amdgcn_sched_barrier(0);
        MFMA_PHASE(1, 1, af, b1f);
        VM_END(tail);
        __builtin_amdgcn_s_barrier();
    }

    // ---------------- epilogue ----------------
    if (mode == 0) {
#pragma unroll
        for (int i = 0; i < 8; ++i) {
#pragma unroll
            for (int e = 0; e < 4; ++e) {
                int grow = arow0 + (i >> 2) * 128 + wr * 64 + (i & 3) * 16 + lquad * 4 + e;
                float na = norms[grow];
#pragma unroll
                for (int j = 0; j < 4; ++j) {
                    int gcol = brow0 + (j >> 1) * 128 + wn * 32 + (j & 1) * 16 + lrow;
                    float v = na + norms[gcol] - 2.f * acc[i][j][e];
                    d2[(size_t)grow * NROW + gcol] = fmaxf(v, 0.f);
                }
            }
        }
    } else {
#pragma unroll
        for (int i = 0; i < 8; ++i) {
#pragma unroll
            for (int j = 0; j < 4; ++j) {
#pragma unroll
                for (int e = 0; e < 4; ++e) {
                    int r = arow0 + (i >> 2) * 128 + wr * 64 + (i & 3) * 16 + lquad * 4 + e;
                    int c = brow0 + (j >> 1) * 128 + wn * 32 + (j & 1) * 16 + lrow;
                    int oc = 0;
                    bool skip = false;
                    if (r < BHALF) {
                        if (c >= BHALF) oc = c - BHALF;           // l01 block
                        else if (c == r) skip = true;             // diag of l00
                        else oc = BHALF + (c < r ? c : c - 1);    // l00 nodiag
                    } else {
                        int rp = r - BHALF;
                        if (c < BHALF) oc = c;                    // l10 block
                        else {
                            int cp = c - BHALF;
                            if (cp == rp) skip = true;            // diag of l11
                            else oc = BHALF + (cp < rp ? cp : cp - 1);
                        }
                    }
                    if (!skip) outlog[(size_t)r * LOGITS_N + oc] = acc[i][j][e];
                }
            }
        }
    }
#undef STAGE_A
#undef STAGE_B
#undef READ_A
#undef READ_B
#undef MFMA_PHASE
#undef VM_END
}

// ---------------- mirror upper triangle of D2 into lower (64x64 tiles) ----------------
__global__ __launch_bounds__(256) void mirror_kernel(float* __restrict__ d2) {
    int bj = blockIdx.x, bi = blockIdx.y;
    if (bi < bj) return;  // only lower-left (incl diagonal) blocks write
    __shared__ float t[64][65];
    int tx = threadIdx.x & 63, ty = threadIdx.x >> 6;  // 64 x 4
#pragma unroll
    for (int r = 0; r < 64; r += 4)
        t[r + ty][tx] = d2[(size_t)(bj * 64 + r + ty) * NROW + bi * 64 + tx];
    __syncthreads();
#pragma unroll
    for (int r = 0; r < 64; r += 4) {
        int gi = bi * 64 + r + ty, gj = bj * 64 + tx;
        if (gi > gj) d2[(size_t)gi * NROW + gj] = t[tx][r + ty];
    }
}

// ---------------- wave-per-row exact rank-32 / rank-512 select + LID ----------------
// 128 values/lane in VGPRs, no block barriers; common-prefix skip via AND/OR reduce.
__global__ __launch_bounds__(256) void select_kernel(const float* __restrict__ d2,
                                                     float* __restrict__ out) {
    int wave = threadIdx.x >> 6, lane = threadIdx.x & 63;
    int row = blockIdx.x * 4 + wave;
    const float4* drow4 = (const float4*)(d2 + (size_t)row * NROW);
    unsigned v[128];
    unsigned andv = 0xFFFFFFFFu, orv = 0u;
#pragma unroll
    for (int j = 0; j < 32; ++j) {
        int idx4 = j * 64 + lane;
        float4 f = drow4[idx4];
        int c0 = idx4 * 4;
        unsigned u0 = __float_as_uint(f.x), u1 = __float_as_uint(f.y);
        unsigned u2 = __float_as_uint(f.z), u3 = __float_as_uint(f.w);
        bool s0 = (c0 == row), s1 = (c0 + 1 == row), s2 = (c0 + 2 == row), s3 = (c0 + 3 == row);
        v[j * 4 + 0] = s0 ? 0xFFFFFFFFu : u0;
        v[j * 4 + 1] = s1 ? 0xFFFFFFFFu : u1;
        v[j * 4 + 2] = s2 ? 0xFFFFFFFFu : u2;
        v[j * 4 + 3] = s3 ? 0xFFFFFFFFu : u3;
        andv &= (s0 ? 0xFFFFFFFFu : u0); orv |= (s0 ? 0u : u0);
        andv &= (s1 ? 0xFFFFFFFFu : u1); orv |= (s1 ? 0u : u1);
        andv &= (s2 ? 0xFFFFFFFFu : u2); orv |= (s2 ? 0u : u2);
        andv &= (s3 ? 0xFFFFFFFFu : u3); orv |= (s3 ? 0u : u3);
    }
#pragma unroll
    for (int off = 32; off; off >>= 1) {
        andv &= __shfl_xor(andv, off);
        orv |= __shfl_xor(orv, off);
    }
    unsigned diff = andv ^ orv;
    int msb = 31 - __clz((int)(diff | 1u));
    unsigned common = (msb == 31) ? 0u : (andv & (0xFFFFFFFFu << (msb + 1)));
    unsigned p1 = common, p2 = common;
    for (int bit = msb; bit >= 0; --bit) {
        unsigned c1 = p1 | (1u << bit), c2 = p2 | (1u << bit);
        unsigned n1 = 0, n2 = 0;
#pragma unroll
        for (int j = 0; j < 128; ++j) { n1 += (v[j] < c1); n2 += (v[j] < c2); }
#pragma unroll
        for (int off = 32; off; off >>= 1) {
            n1 += __shfl_xor(n1, off);
            n2 += __shfl_xor(n2, off);
        }
        if (n1 < 32u) p1 = c1;
        if (n2 < 512u) p2 = c2;
    }
    float dk1 = sqrtf(__uint_as_float(p1));
    float dk2 = sqrtf(__uint_as_float(p2));
    float s1 = 0.f, s2 = 0.f;
#pragma unroll
    for (int j = 0; j < 128; ++j) {
        unsigned b = v[j];
        if (b < p2) {
            float d = sqrtf(__uint_as_float(b));
            s2 += logf(d / dk2 + 1e-12f);
            if (b < p1) s1 += logf(d / dk1 + 1e-12f);
        }
    }
#pragma unroll
    for (int off = 32; off; off >>= 1) {
        s1 += __shfl_xor(s1, off);
        s2 += __shfl_xor(s2, off);
    }
    if (lane == 0) {
        out[(size_t)OUT_LIDS32 + row] = -32.f / s1;
        out[(size_t)OUT_LIDS512 + row] = -512.f / s2;
    }
}

extern "C" void kernel_launch(void* const* d_in, const int* in_sizes, int n_in,
                              void* d_out, int out_size, void* d_ws, size_t ws_size,
                              hipStream_t stream) {
    const float* fe0 = (const float*)d_in[0];
    const float* fe1 = (const float*)d_in[1];
    const float* p0 = (const float*)d_in[2];
    const float* p1 = (const float*)d_in[3];
    const float* z0 = (const float*)d_in[4];
    const float* z1 = (const float*)d_in[5];
    const float* cls0 = (const float*)d_in[6];
    const float* cls1 = (const float*)d_in[7];
    const int* labels = (const int*)d_in[8];
    float* out = (float*)d_out;

    // workspace layout
    char* ws = (char*)d_ws;
    float* D2 = (float*)ws;                                        // 268435456 B
    bf16* FEH = (bf16*)(ws + 268435456UL);                         // 33554432 B
    bf16* FEL = (bf16*)(ws + 268435456UL + 33554432UL);            // 33554432 B
    bf16* OH = (bf16*)(ws + 268435456UL + 2 * 33554432UL);         // 4194304 B
    float* NORMS = (float*)(ws + 268435456UL + 2 * 33554432UL + 4194304UL);  // 32 KB

    init_kernel<<<32, 256, 0, stream>>>(out);
    split_fe_kernel<<<8192, 256, 0, stream>>>(fe0, fe1, FEH, FEL, NORMS);
    norm_split_p_kernel<<<8192, 256, 0, stream>>>(p0, p1, OH);
    byol_kernel<<<1024, 256, 0, stream>>>(p0, p1, z0, z1, out);
    online_kernel<<<2048, 256, 0, stream>>>(cls0, cls1, labels, out);
    // merged GEMM: blocks [0,528) = d2 triangle tiles, [528,1552) = logits tiles
    gemm_kernel<<<G0TILES + G1TILES, 512, 0, stream>>>(FEH, FEL, OH, NORMS, D2, out + OUT_LOGITS);
    mirror_kernel<<<dim3(128, 128), 256, 0, stream>>>(D2);
    select_kernel<<<2048, 256, 0, stream>>>(D2, out);
}

// Round 4
// 1251.347 us; speedup vs baseline: 1.0327x; 1.0327x over previous
//
#include <hip/hip_runtime.h>
#include <math.h>

typedef __bf16 bf16;
typedef __bf16 bf16x8 __attribute__((ext_vector_type(8)));
typedef __bf16 bf16x4 __attribute__((ext_vector_type(4)));
typedef float f32x4 __attribute__((ext_vector_type(4)));

#define NROW 8192
#define BHALF 4096
#define DFE 2048
#define DP 256
#define NCLS 1000

#define LOGITS_N 8191
#define OUT_LOGITS 2
#define OUT_LABELS (2 + 8192 * 8191)
#define OUT_LIDS32 (OUT_LABELS + 8192)
#define OUT_LIDS512 (OUT_LIDS32 + 8192)

#define G0TILES 528   // mode-0: 256x256 tiles, upper triangle (tm <= tn), 32x32 tile grid
#define G1TILES 1024  // mode-1: 32 x 32 full grid (logits), 256x256 tiles

// async 16B global->LDS (dest = wave-uniform base + lane*16)
__device__ inline void gload16(const bf16* g, bf16* l) {
    __builtin_amdgcn_global_load_lds((const __attribute__((address_space(1))) void*)g,
                                     (__attribute__((address_space(3))) void*)l, 16, 0, 0);
}

// ---------------- init: zero scalar accumulators + write labels ----------------
__global__ __launch_bounds__(256) void init_kernel(float* out) {
    int i = blockIdx.x * 256 + threadIdx.x;
    if (i < 2) out[i] = 0.f;
    if (i < NROW) out[(size_t)OUT_LABELS + i] = (float)(i & (BHALF - 1));
}

// ---------------- split fe into bf16 hi/lo + row norms ----------------
__global__ __launch_bounds__(256) void split_fe_kernel(const float* __restrict__ fe0,
                                                       const float* __restrict__ fe1,
                                                       bf16* __restrict__ feh,
                                                       bf16* __restrict__ fel,
                                                       float* __restrict__ norms) {
    int row = blockIdx.x, tid = threadIdx.x;
    const float* src = (row < BHALF) ? fe0 + (size_t)row * DFE
                                     : fe1 + (size_t)(row - BHALF) * DFE;
    float ss = 0.f;
#pragma unroll
    for (int pass = 0; pass < 2; ++pass) {
        int c = (pass * 256 + tid) * 4;
        float4 v = *(const float4*)(src + c);
        ss += v.x * v.x + v.y * v.y + v.z * v.z + v.w * v.w;
        bf16 h0 = (bf16)v.x, h1 = (bf16)v.y, h2 = (bf16)v.z, h3 = (bf16)v.w;
        bf16 l0 = (bf16)(v.x - (float)h0), l1 = (bf16)(v.y - (float)h1);
        bf16 l2 = (bf16)(v.z - (float)h2), l3 = (bf16)(v.w - (float)h3);
        bf16x4 hv = {h0, h1, h2, h3};
        bf16x4 lv = {l0, l1, l2, l3};
        *(bf16x4*)(feh + (size_t)row * DFE + c) = hv;
        *(bf16x4*)(fel + (size_t)row * DFE + c) = lv;
    }
#pragma unroll
    for (int off = 32; off; off >>= 1) ss += __shfl_down(ss, off);
    __shared__ float red[4];
    if ((tid & 63) == 0) red[tid >> 6] = ss;
    __syncthreads();
    if (tid == 0) norms[row] = red[0] + red[1] + red[2] + red[3];
}

// ---------------- l2-normalize p -> bf16 (HH-only logits path) ----------------
__global__ __launch_bounds__(256) void norm_split_p_kernel(const float* __restrict__ p0,
                                                           const float* __restrict__ p1,
                                                           bf16* __restrict__ oh) {
    int row = blockIdx.x, tid = threadIdx.x;
    const float* src = (row < BHALF) ? p0 + (size_t)row * DP
                                     : p1 + (size_t)(row - BHALF) * DP;
    float x = src[tid];
    float ss = x * x;
#pragma unroll
    for (int off = 32; off; off >>= 1) ss += __shfl_down(ss, off);
    __shared__ float red[4];
    if ((tid & 63) == 0) red[tid >> 6] = ss;
    __syncthreads();
    float tot = red[0] + red[1] + red[2] + red[3];
    float rn = 1.f / fmaxf(sqrtf(tot), 1e-12f);
    oh[(size_t)row * DP + tid] = (bf16)(x * rn);
}

// ---------------- BYOL main loss ----------------
__device__ inline float dot4(float4 a, float4 b) {
    return a.x * b.x + a.y * b.y + a.z * b.z + a.w * b.w;
}

__global__ __launch_bounds__(256) void byol_kernel(const float* __restrict__ p0,
                                                   const float* __restrict__ p1,
                                                   const float* __restrict__ z0,
                                                   const float* __restrict__ z1,
                                                   float* out) {
    int tid = threadIdx.x, wave = tid >> 6, lane = tid & 63;
    int row = blockIdx.x * 4 + wave;
    size_t base = (size_t)row * DP + lane * 4;
    float4 a0 = *(const float4*)(p0 + base);
    float4 b0 = *(const float4*)(z1 + base);
    float4 a1 = *(const float4*)(p1 + base);
    float4 b1 = *(const float4*)(z0 + base);
    float pp0 = dot4(a0, a0), zz0 = dot4(b0, b0), pz0 = dot4(a0, b0);
    float pp1 = dot4(a1, a1), zz1 = dot4(b1, b1), pz1 = dot4(a1, b1);
#pragma unroll
    for (int off = 32; off; off >>= 1) {
        pp0 += __shfl_down(pp0, off); zz0 += __shfl_down(zz0, off); pz0 += __shfl_down(pz0, off);
        pp1 += __shfl_down(pp1, off); zz1 += __shfl_down(zz1, off); pz1 += __shfl_down(pz1, off);
    }
    __shared__ float red[4];
    if (lane == 0) {
        float c0 = pz0 / (fmaxf(sqrtf(pp0), 1e-12f) * fmaxf(sqrtf(zz0), 1e-12f));
        float c1 = pz1 / (fmaxf(sqrtf(pp1), 1e-12f) * fmaxf(sqrtf(zz1), 1e-12f));
        red[wave] = (2.f - 2.f * c0) + (2.f - 2.f * c1);
    }
    __syncthreads();
    if (tid == 0) atomicAdd(out, (red[0] + red[1] + red[2] + red[3]) * (1.f / 4096.f));
}

// ---------------- online linear-probe CE loss ----------------
__global__ __launch_bounds__(256) void online_kernel(const float* __restrict__ cls0,
                                                     const float* __restrict__ cls1,
                                                     const int* __restrict__ labels,
                                                     float* out) {
    int tid = threadIdx.x, wave = tid >> 6, lane = tid & 63;
    int row = blockIdx.x * 4 + wave;
    const float* src = (row < BHALF) ? cls0 + (size_t)row * NCLS
                                     : cls1 + (size_t)(row - BHALF) * NCLS;
    int lbl = labels[row & (BHALF - 1)];
    float xs[16];
    float mx = -INFINITY;
#pragma unroll
    for (int j = 0; j < 16; ++j) {
        int c = lane + j * 64;
        xs[j] = (c < NCLS) ? src[c] : -INFINITY;
        mx = fmaxf(mx, xs[j]);
    }
#pragma unroll
    for (int off = 32; off; off >>= 1) mx = fmaxf(mx, __shfl_xor(mx, off));
    float se = 0.f;
#pragma unroll
    for (int j = 0; j < 16; ++j) se += expf(xs[j] - mx);
#pragma unroll
    for (int off = 32; off; off >>= 1) se += __shfl_xor(se, off);
    __shared__ float red[4];
    if (lane == 0) red[wave] = src[lbl] - mx - logf(se);
    __syncthreads();
    if (tid == 0) atomicAdd(out + 1, -(red[0] + red[1] + red[2] + red[3]) * (1.f / 8192.f));
}

// ---------------- 256x256-tile software-pipelined GEMM (mode0: d2, mode1: logits) --------
// 8 waves (2M x 4N), per-wave output 128x64 = acc[8][4]. LDS 128KB: 2 buf x (A[256][64] +
// B[256][64]) bf16. 4 phases per K-tile, quadrants Q0=(0,0) Q1=(0,1) Q2=(1,0) Q3=(1,1).
// KEY (vs prior rounds): ds_reads issue ONE PHASE AHEAD and are waited with COUNTED
// lgkmcnt, so LDS reads flow during MFMA windows:
//   P0: issue B1(t)[4]  -> lgkmcnt(4)  -> Q0 (A0xB0)
//   P1: issue A1(t)[8]  -> lgkmcnt(8)  -> Q1 (A0xB1) -> barrier (read-issue fence)
//   P2: lgkmcnt(0) -> burst-stage tile t+2 [8 gloads] -> Q2 (A1xB0)
//       -> vmcnt(8) (publish buf t+1; never 0 mid-loop) -> barrier
//   P3: issue A0,B0(t+1)[12] from published buf -> Q3 (A1xB1), NO wait
// 2 barriers + 1 vmcnt per K-tile. Staging lookahead = 4 phases (~1000cy >= HBM lat).
// XOR-swizzle (verified): phys grp = logical grp ^ (row&7); staging pre-swizzles source.
__global__ __launch_bounds__(512, 2) void gemm_kernel(const bf16* __restrict__ Hp,
                                                      const bf16* __restrict__ Lp,
                                                      const bf16* __restrict__ OHp,
                                                      const float* __restrict__ norms,
                                                      float* __restrict__ d2,
                                                      float* __restrict__ outlog) {
    __shared__ bf16 sm[2][32768];  // per buf: A[256][64] @0, B[256][64] @16384 elts
    int tid = threadIdx.x, lane = tid & 63, wave = tid >> 6;
    int wr = wave >> 2, wn = wave & 3;
    int lrow = lane & 15, lquad = lane >> 4, r7 = lrow & 7, pg = lquad ^ r7;
    int rsub = lane >> 3, grp = lane & 7, lg = grp ^ rsub;

    int bid = blockIdx.x;
    int mode, tm, tn, ksh;
    const bf16 *Hmat, *Lmat;
    int Kd;
    if (bid < G0TILES) {
        mode = 0;
        int sw = (bid & 7) * (G0TILES / 8) + (bid >> 3);  // XCD-bijective (528 = 8*66)
        int i = 0;
        while ((i + 1) * (64 - i) / 2 <= sw) ++i;  // prefix(m) = m*(65-m)/2
        tm = i;
        tn = tm + (sw - i * (65 - i) / 2);
        Hmat = Hp; Lmat = Lp; Kd = DFE; ksh = 5;
    } else {
        mode = 1;
        int id = bid - G0TILES;
        int sw = (id & 7) * (G1TILES / 8) + (id >> 3);    // 1024 = 8*128
        tm = sw & 31; tn = sw >> 5;
        Hmat = OHp; Lmat = OHp; Kd = DP; ksh = 2;
    }
    int NT = (mode == 0 ? 3 : 1) << ksh;  // 96 or 4
    int kmask = (1 << ksh) - 1;
    int arow0 = tm * 256, brow0 = tn * 256;
    size_t delta = (size_t)(Lmat - Hmat);  // 0 in mode 1

    // per-wave staging base (pre-swizzled source: fetch logical group lg for phys grp)
    const bf16* baseA0 = Hmat + (size_t)(arow0 + wave * 8 + rsub) * Kd + lg * 8;
    const bf16* baseB0 = Hmat + (size_t)(brow0 + wave * 8 + rsub) * Kd + lg * 8;

    // fragment LDS byte offsets (ks=1 half is ^64)
    int aoffbase[2], boffbase[2];
    aoffbase[0] = (wr * 64 + lrow) * 128 + pg * 16;
    aoffbase[1] = aoffbase[0] + 128 * 128;
    boffbase[0] = 32768 + (wn * 32 + lrow) * 128 + pg * 16;
    boffbase[1] = boffbase[0] + 128 * 128;

    f32x4 acc[8][4];
    f32x4 zz = {0.f, 0.f, 0.f, 0.f};
#pragma unroll
    for (int i = 0; i < 8; ++i)
#pragma unroll
        for (int j = 0; j < 4; ++j) acc[i][j] = zz;

// burst-stage ALL of K-tile tau (A0,A1,B0,B1 = 8 gload16/wave) into dstbuf
#define STAGE_ALL(tau, dstbuf)                                                    \
    do {                                                                          \
        int tau_ = (tau);                                                         \
        if (tau_ < NT) {                                                          \
            int ch_ = tau_ >> ksh;                                                \
            size_t dA_ = (ch_ == 1) ? delta : 0;                                  \
            size_t dB_ = (ch_ == 2) ? delta : 0;                                  \
            int k_ = (tau_ & kmask) << 6;                                         \
            bf16* da_ = (dstbuf) + wave * 512;                                    \
            bf16* db_ = (dstbuf) + 16384 + wave * 512;                            \
            _Pragma("unroll") for (int h = 0; h < 2; ++h) {                       \
                gload16(baseA0 + (size_t)(h * 128) * Kd + dA_ + k_, da_ + h * 8192);          \
                gload16(baseA0 + (size_t)(h * 128 + 64) * Kd + dA_ + k_, da_ + h * 8192 + 4096); \
                gload16(baseB0 + (size_t)(h * 128) * Kd + dB_ + k_, db_ + h * 8192);          \
                gload16(baseB0 + (size_t)(h * 128 + 64) * Kd + dB_ + k_, db_ + h * 8192 + 4096); \
            }                                                                     \
        }                                                                         \
    } while (0)

#define READ_A(AF, MI, SB)                                                        \
    do {                                                                          \
        _Pragma("unroll") for (int f = 0; f < 4; ++f) {                           \
            int off_ = aoffbase[(MI)] + f * 2048;                                 \
            AF[f][0] = *(const bf16x8*)((SB) + off_);                             \
            AF[f][1] = *(const bf16x8*)((SB) + (off_ ^ 64));                      \
        }                                                                         \
    } while (0)

#define READ_B(BF, NI, SB)                                                        \
    do {                                                                          \
        _Pragma("unroll") for (int jj = 0; jj < 2; ++jj) {                        \
            int off_ = boffbase[(NI)] + jj * 2048;                                \
            BF[jj][0] = *(const bf16x8*)((SB) + off_);                            \
            BF[jj][1] = *(const bf16x8*)((SB) + (off_ ^ 64));                     \
        }                                                                         \
    } while (0)

#define MFMA_PHASE(MI, NI, AF, BF)                                                \
    do {                                                                          \
        __builtin_amdgcn_s_setprio(1);                                            \
        _Pragma("unroll") for (int f = 0; f < 4; ++f)                             \
            _Pragma("unroll") for (int jj = 0; jj < 2; ++jj) {                    \
                acc[(MI)*4 + f][(NI)*2 + jj] = __builtin_amdgcn_mfma_f32_16x16x32_bf16( \
                    AF[f][0], BF[jj][0], acc[(MI)*4 + f][(NI)*2 + jj], 0, 0, 0);  \
                acc[(MI)*4 + f][(NI)*2 + jj] = __builtin_amdgcn_mfma_f32_16x16x32_bf16( \
                    AF[f][1], BF[jj][1], acc[(MI)*4 + f][(NI)*2 + jj], 0, 0, 0);  \
            }                                                                     \
        __builtin_amdgcn_s_setprio(0);                                            \
    } while (0)

    bf16x8 af[4][2];   // A0 frags of current tile (later: of next tile)
    bf16x8 af2[4][2];  // A1 frags of current tile
    bf16x8 b0f[2][2];  // B0 frags
    bf16x8 b1f[2][2];  // B1 frags
    const char* S0 = (const char*)sm[0];
    const char* S1 = (const char*)sm[1];

    // prologue: burst-stage tiles 0 and 1 (16 loads), wait buf0 (keep buf1's 8 in flight)
    STAGE_ALL(0, sm[0]);
    STAGE_ALL(1, sm[1]);
    asm volatile("s_waitcnt vmcnt(8)" ::: "memory");
    __builtin_amdgcn_s_barrier();
    // pre-issue tile-0 A0+B0 fragment reads (12 ds) — the loop's "issued at P3(t-1)"
    READ_A(af, 0, S0);
    READ_B(b0f, 0, S0);

    for (int t = 0; t < NT; ++t) {
        const char* Sb = (t & 1) ? S1 : S0;
        const char* Sbn = (t & 1) ? S0 : S1;
        bf16* ownbuf = sm[t & 1];

        // ---- P0: issue B1(t) reads; wait the 12 A0/B0 reads; Q0 = A0 x B0
        READ_B(b1f, 1, Sb);
        asm volatile("s_waitcnt lgkmcnt(4)" ::: "memory");
        __builtin_amdgcn_sched_barrier(0);
        MFMA_PHASE(0, 0, af, b0f);

        // ---- P1: issue A1(t) reads; wait B1; Q1 = A0 x B1; read-issue fence barrier
        READ_A(af2, 1, Sb);
        asm volatile("s_waitcnt lgkmcnt(8)" ::: "memory");
        __builtin_amdgcn_sched_barrier(0);
        MFMA_PHASE(0, 1, af, b1f);
        __builtin_amdgcn_s_barrier();  // β1: all waves' reads of buf(t) issued

        // ---- P2: drain A1 reads; burst-stage tile t+2 into own buf; Q2 = A1 x B0
        asm volatile("s_waitcnt lgkmcnt(0)" ::: "memory");
        __builtin_amdgcn_sched_barrier(0);
        STAGE_ALL(t + 2, ownbuf);
        MFMA_PHASE(1, 0, af2, b0f);
        if (t + 2 < NT) asm volatile("s_waitcnt vmcnt(8)" ::: "memory");
        else            asm volatile("s_waitcnt vmcnt(0)" ::: "memory");
        __builtin_amdgcn_s_barrier();  // β2: publish buf(t+1)

        // ---- P3: issue A0/B0(t+1) reads from published buf; Q3 = A1 x B1 (no wait)
        if (t + 1 < NT) {
            READ_A(af, 0, Sbn);
            READ_B(b0f, 0, Sbn);
        }
        __builtin_amdgcn_sched_barrier(0);
        MFMA_PHASE(1, 1, af2, b1f);
    }

    // ---------------- epilogue ----------------
    if (mode == 0) {
#pragma unroll
        for (int i = 0; i < 8; ++i) {
#pragma unroll
            for (int e = 0; e < 4; ++e) {
                int grow = arow0 + (i >> 2) * 128 + wr * 64 + (i & 3) * 16 + lquad * 4 + e;
                float na = norms[grow];
#pragma unroll
                for (int j = 0; j < 4; ++j) {
                    int gcol = brow0 + (j >> 1) * 128 + wn * 32 + (j & 1) * 16 + lrow;
                    float v = na + norms[gcol] - 2.f * acc[i][j][e];
                    d2[(size_t)grow * NROW + gcol] = fmaxf(v, 0.f);
                }
            }
        }
    } else {
#pragma unroll
        for (int i = 0; i < 8; ++i) {
#pragma unroll
            for (int j = 0; j < 4; ++j) {
#pragma unroll
                for (int e = 0; e < 4; ++e) {
                    int r = arow0 + (i >> 2) * 128 + wr * 64 + (i & 3) * 16 + lquad * 4 + e;
                    int c = brow0 + (j >> 1) * 128 + wn * 32 + (j & 1) * 16 + lrow;
                    int oc = 0;
                    bool skip = false;
                    if (r < BHALF) {
                        if (c >= BHALF) oc = c - BHALF;           // l01 block
                        else if (c == r) skip = true;             // diag of l00
                        else oc = BHALF + (c < r ? c : c - 1);    // l00 nodiag
                    } else {
                        int rp = r - BHALF;
                        if (c < BHALF) oc = c;                    // l10 block
                        else {
                            int cp = c - BHALF;
                            if (cp == rp) skip = true;            // diag of l11
                            else oc = BHALF + (cp < rp ? cp : cp - 1);
                        }
                    }
                    if (!skip) outlog[(size_t)r * LOGITS_N + oc] = acc[i][j][e];
                }
            }
        }
    }
#undef STAGE_ALL
#undef READ_A
#undef READ_B
#undef MFMA_PHASE
}

// ---------------- mirror upper triangle of D2 into lower (64x64 tiles) ----------------
__global__ __launch_bounds__(256) void mirror_kernel(float* __restrict__ d2) {
    int bj = blockIdx.x, bi = blockIdx.y;
    if (bi < bj) return;  // only lower-left (incl diagonal) blocks write
    __shared__ float t[64][65];
    int tx = threadIdx.x & 63, ty = threadIdx.x >> 6;  // 64 x 4
#pragma unroll
    for (int r = 0; r < 64; r += 4)
        t[r + ty][tx] = d2[(size_t)(bj * 64 + r + ty) * NROW + bi * 64 + tx];
    __syncthreads();
#pragma unroll
    for (int r = 0; r < 64; r += 4) {
        int gi = bi * 64 + r + ty, gj = bj * 64 + tx;
        if (gi > gj) d2[(size_t)gi * NROW + gj] = t[tx][r + ty];
    }
}

// ---------------- wave-per-row exact rank-32 / rank-512 select + LID ----------------
// 128 values/lane in VGPRs, no block barriers; common-prefix skip via AND/OR reduce.
__global__ __launch_bounds__(256) void select_kernel(const float* __restrict__ d2,
                                                     float* __restrict__ out) {
    int wave = threadIdx.x >> 6, lane = threadIdx.x & 63;
    int row = blockIdx.x * 4 + wave;
    const float4* drow4 = (const float4*)(d2 + (size_t)row * NROW);
    unsigned v[128];
    unsigned andv = 0xFFFFFFFFu, orv = 0u;
#pragma unroll
    for (int j = 0; j < 32; ++j) {
        int idx4 = j * 64 + lane;
        float4 f = drow4[idx4];
        int c0 = idx4 * 4;
        unsigned u0 = __float_as_uint(f.x), u1 = __float_as_uint(f.y);
        unsigned u2 = __float_as_uint(f.z), u3 = __float_as_uint(f.w);
        bool s0 = (c0 == row), s1 = (c0 + 1 == row), s2 = (c0 + 2 == row), s3 = (c0 + 3 == row);
        v[j * 4 + 0] = s0 ? 0xFFFFFFFFu : u0;
        v[j * 4 + 1] = s1 ? 0xFFFFFFFFu : u1;
        v[j * 4 + 2] = s2 ? 0xFFFFFFFFu : u2;
        v[j * 4 + 3] = s3 ? 0xFFFFFFFFu : u3;
        andv &= (s0 ? 0xFFFFFFFFu : u0); orv |= (s0 ? 0u : u0);
        andv &= (s1 ? 0xFFFFFFFFu : u1); orv |= (s1 ? 0u : u1);
        andv &= (s2 ? 0xFFFFFFFFu : u2); orv |= (s2 ? 0u : u2);
        andv &= (s3 ? 0xFFFFFFFFu : u3); orv |= (s3 ? 0u : u3);
    }
#pragma unroll
    for (int off = 32; off; off >>= 1) {
        andv &= __shfl_xor(andv, off);
        orv |= __shfl_xor(orv, off);
    }
    unsigned diff = andv ^ orv;
    int msb = 31 - __clz((int)(diff | 1u));
    unsigned common = (msb == 31) ? 0u : (andv & (0xFFFFFFFFu << (msb + 1)));
    unsigned p1 = common, p2 = common;
    for (int bit = msb; bit >= 0; --bit) {
        unsigned c1 = p1 | (1u << bit), c2 = p2 | (1u << bit);
        unsigned n1 = 0, n2 = 0;
#pragma unroll
        for (int j = 0; j < 128; ++j) { n1 += (v[j] < c1); n2 += (v[j] < c2); }
#pragma unroll
        for (int off = 32; off; off >>= 1) {
            n1 += __shfl_xor(n1, off);
            n2 += __shfl_xor(n2, off);
        }
        if (n1 < 32u) p1 = c1;
        if (n2 < 512u) p2 = c2;
    }
    float dk1 = sqrtf(__uint_as_float(p1));
    float dk2 = sqrtf(__uint_as_float(p2));
    float s1 = 0.f, s2 = 0.f;
#pragma unroll
    for (int j = 0; j < 128; ++j) {
        unsigned b = v[j];
        if (b < p2) {
            float d = sqrtf(__uint_as_float(b));
            s2 += logf(d / dk2 + 1e-12f);
            if (b < p1) s1 += logf(d / dk1 + 1e-12f);
        }
    }
#pragma unroll
    for (int off = 32; off; off >>= 1) {
        s1 += __shfl_xor(s1, off);
        s2 += __shfl_xor(s2, off);
    }
    if (lane == 0) {
        out[(size_t)OUT_LIDS32 + row] = -32.f / s1;
        out[(size_t)OUT_LIDS512 + row] = -512.f / s2;
    }
}

extern "C" void kernel_launch(void* const* d_in, const int* in_sizes, int n_in,
                              void* d_out, int out_size, void* d_ws, size_t ws_size,
                              hipStream_t stream) {
    const float* fe0 = (const float*)d_in[0];
    const float* fe1 = (const float*)d_in[1];
    const float* p0 = (const float*)d_in[2];
    const float* p1 = (const float*)d_in[3];
    const float* z0 = (const float*)d_in[4];
    const float* z1 = (const float*)d_in[5];
    const float* cls0 = (const float*)d_in[6];
    const float* cls1 = (const float*)d_in[7];
    const int* labels = (const int*)d_in[8];
    float* out = (float*)d_out;

    // workspace layout
    char* ws = (char*)d_ws;
    float* D2 = (float*)ws;                                        // 268435456 B
    bf16* FEH = (bf16*)(ws + 268435456UL);                         // 33554432 B
    bf16* FEL = (bf16*)(ws + 268435456UL + 33554432UL);            // 33554432 B
    bf16* OH = (bf16*)(ws + 268435456UL + 2 * 33554432UL);         // 4194304 B
    float* NORMS = (float*)(ws + 268435456UL + 2 * 33554432UL + 4194304UL);  // 32 KB

    init_kernel<<<32, 256, 0, stream>>>(out);
    split_fe_kernel<<<8192, 256, 0, stream>>>(fe0, fe1, FEH, FEL, NORMS);
    norm_split_p_kernel<<<8192, 256, 0, stream>>>(p0, p1, OH);
    byol_kernel<<<1024, 256, 0, stream>>>(p0, p1, z0, z1, out);
    online_kernel<<<2048, 256, 0, stream>>>(cls0, cls1, labels, out);
    // merged GEMM: blocks [0,528) = d2 triangle tiles, [528,1552) = logits tiles
    gemm_kernel<<<G0TILES + G1TILES, 512, 0, stream>>>(FEH, FEL, OH, NORMS, D2, out + OUT_LOGITS);
    mirror_kernel<<<dim3(128, 128), 256, 0, stream>>>(D2);
    select_kernel<<<2048, 256, 0, stream>>>(D2, out);
}